// Round 1
// baseline (33.436 us; speedup 1.0000x reference)
//
#include <hip/hip_runtime.h>
#include <hip/hip_bf16.h>

#define BB 8
#define NN 256
#define DD 64
#define HH 8
#define PP 4

#define TI 128
#define TJ 16

typedef __attribute__((ext_vector_type(8))) short bf16x8;
typedef __attribute__((ext_vector_type(4))) float f32x4;

static __device__ __forceinline__ unsigned short bfbits(float f) {
  union { float f; unsigned u; } v; v.f = f;
  unsigned u = v.u;
  u += 0x7FFFu + ((u >> 16) & 1u);   // round-to-nearest-even
  return (unsigned short)(u >> 16);
}

static __device__ __forceinline__ bf16x8 pack8(float4 a, float4 b) {
  bf16x8 v;
  v[0] = (short)bfbits(a.x); v[1] = (short)bfbits(a.y);
  v[2] = (short)bfbits(a.z); v[3] = (short)bfbits(a.w);
  v[4] = (short)bfbits(b.x); v[5] = (short)bfbits(b.y);
  v[6] = (short)bfbits(b.z); v[7] = (short)bfbits(b.w);
  return v;
}

// Z[b][h][ki][j][d] = sum_kj conv_w[h][d][ki][kj] * x[b][j+kj-1][d]   (bf16 out)
__global__ __launch_bounds__(256)
void z_kernel(const float* __restrict__ x, const float* __restrict__ conv_w,
              unsigned short* __restrict__ z) {
  int t = blockIdx.x * 256 + threadIdx.x;        // B*H*3*N*(D/4) = 786432 threads
  int d4  = (t & 15) * 4;
  int row = t >> 4;                              // ((b*H + h)*3 + ki)*N + j
  int j   = row & (NN - 1);
  int r2  = row >> 8;
  int ki  = r2 % 3;
  int r3  = r2 / 3;
  int h   = r3 & (HH - 1);
  int b   = r3 >> 3;

  float a0 = 0.f, a1 = 0.f, a2 = 0.f, a3 = 0.f;
#pragma unroll
  for (int kj = 0; kj < 3; ++kj) {
    int js = j + kj - 1;
    if (js < 0 || js >= NN) continue;
    float4 xv = *(const float4*)(x + ((size_t)(b * NN + js)) * DD + d4);
    float w0 = conv_w[((h * DD + d4 + 0) * 3 + ki) * 3 + kj];
    float w1 = conv_w[((h * DD + d4 + 1) * 3 + ki) * 3 + kj];
    float w2 = conv_w[((h * DD + d4 + 2) * 3 + ki) * 3 + kj];
    float w3 = conv_w[((h * DD + d4 + 3) * 3 + ki) * 3 + kj];
    a0 += w0 * xv.x; a1 += w1 * xv.y; a2 += w2 * xv.z; a3 += w3 * xv.w;
  }
  ushort4 o;
  o.x = bfbits(a0); o.y = bfbits(a1); o.z = bfbits(a2); o.w = bfbits(a3);
  *(ushort4*)(z + (size_t)row * DD + d4) = o;
}

// out[b,h,i,j] = (sum_ki sum_d x[b,i+ki-1,d]*Z[b,h,ki][j,d] + conv_b[h]) * (edge[b,i,j,:]·edge_w[h,:])
__global__ __launch_bounds__(256, 1)
void main_kernel(const float* __restrict__ x, const unsigned short* __restrict__ z,
                 const float* __restrict__ edge, const float* __restrict__ conv_b,
                 const float* __restrict__ edge_w, float* __restrict__ out) {
  const int bid = blockIdx.x;            // b*(2*16) + it*16 + jt
  const int jt = bid & 15;
  const int it = (bid >> 4) & 1;
  const int b  = bid >> 5;
  const int j0 = jt * TJ;
  const int i0 = it * TI;
  const int lane = threadIdx.x & 63;
  const int wave = threadIdx.x >> 6;
  const int lrow = lane & 15;            // frag row (A) / col (B,C)
  const int lk   = lane >> 4;            // k-chunk 0..3

  // per-head constants
  float4 ew[HH];
  float  cb[HH];
#pragma unroll
  for (int h = 0; h < HH; ++h) {
    ew[h] = *(const float4*)(edge_w + h * PP);
    cb[h] = conv_b[h];
  }

  // A fragments: [mf(2)][ki(3)][dh(2)], rows iw..iw+31 with +-1 halo, fp32->bf16 on the fly
  const int iw = i0 + wave * 32;
  bf16x8 a[2][3][2];
#pragma unroll
  for (int mf = 0; mf < 2; ++mf) {
#pragma unroll
    for (int ki = 0; ki < 3; ++ki) {
      int r = iw + mf * 16 + lrow + ki - 1;
      bool ok = (r >= 0) && (r < NN);
#pragma unroll
      for (int dh = 0; dh < 2; ++dh) {
        bf16x8 v = {0, 0, 0, 0, 0, 0, 0, 0};
        if (ok) {
          const float* px = x + ((size_t)(b * NN + r)) * DD + dh * 32 + lk * 8;
          float4 f0 = *(const float4*)(px);
          float4 f1 = *(const float4*)(px + 4);
          v = pack8(f0, f1);
        }
        a[mf][ki][dh] = v;
      }
    }
  }

  f32x4 acc[HH][2];
#pragma unroll
  for (int h = 0; h < HH; ++h)
#pragma unroll
    for (int mf = 0; mf < 2; ++mf)
      acc[h][mf] = (f32x4){0.f, 0.f, 0.f, 0.f};

#pragma unroll
  for (int h = 0; h < HH; ++h) {
    bf16x8 bz[3][2];
#pragma unroll
    for (int ki = 0; ki < 3; ++ki) {
#pragma unroll
      for (int dh = 0; dh < 2; ++dh) {
        const unsigned short* pz =
            z + (((size_t)((b * HH + h) * 3 + ki) * NN + (j0 + lrow)) * DD + dh * 32 + lk * 8);
        bz[ki][dh] = *(const bf16x8*)pz;
      }
    }
#pragma unroll
    for (int mf = 0; mf < 2; ++mf)
#pragma unroll
      for (int ki = 0; ki < 3; ++ki)
#pragma unroll
        for (int dh = 0; dh < 2; ++dh)
          acc[h][mf] = __builtin_amdgcn_mfma_f32_16x16x32_bf16(
              a[mf][ki][dh], bz[ki][dh], acc[h][mf], 0, 0, 0);
  }

  // epilogue: edge projection + scale + store
#pragma unroll
  for (int mf = 0; mf < 2; ++mf) {
#pragma unroll
    for (int r = 0; r < 4; ++r) {
      int i = iw + mf * 16 + lk * 4 + r;
      int j = j0 + lrow;
      float4 e4 = *(const float4*)(edge + ((size_t)(b * NN + i) * NN + j) * PP);
#pragma unroll
      for (int h = 0; h < HH; ++h) {
        float eh = e4.x * ew[h].x + e4.y * ew[h].y + e4.z * ew[h].z + e4.w * ew[h].w;
        out[((size_t)(b * HH + h) * NN + i) * NN + j] = (acc[h][mf][r] + cb[h]) * eh;
      }
    }
  }
}

extern "C" void kernel_launch(void* const* d_in, const int* in_sizes, int n_in,
                              void* d_out, int out_size, void* d_ws, size_t ws_size,
                              hipStream_t stream) {
  const float* x      = (const float*)d_in[0];
  const float* edge   = (const float*)d_in[1];
  const float* conv_w = (const float*)d_in[2];
  const float* conv_b = (const float*)d_in[3];
  const float* edge_w = (const float*)d_in[4];
  float* out = (float*)d_out;
  unsigned short* z = (unsigned short*)d_ws;   // B*H*3*N*D bf16 = 6.3 MB

  z_kernel<<<(BB * HH * 3 * NN * (DD / 4)) / 256, 256, 0, stream>>>(x, conv_w, z);
  main_kernel<<<BB * (NN / TI) * (NN / TJ), 256, 0, stream>>>(x, z, edge, conv_b, edge_w, out);
}